// Round 2
// baseline (55.012 us; speedup 1.0000x reference)
//
#include <hip/hip_runtime.h>

// InvariantPolynomial: out = sum_e xl[oi[e]] * xr[e] * f(|pos_e|)
// f depends only on d=|pos| (sh[:, :1] == 1); tabulated in a 2048-entry LUT
// over [0,5] (f==0 in fp32 beyond d=5), linear interp (rel err ~1e-4 << 2e-2 tol).
//
// ws layout: [0,8KB) float LUT; [8KB,16KB) double partials[1024]; [16KB] counter.

#define TN   2048
#define DMAXF 5.0f
#define NBLK 1024
#define TPB  256
#define EPT  8

// 1/sqrt(E[silu(z)^2]), z~N(0,1); matched reference exactly in R1 (absmax 0.0).
__device__ __constant__ float kSiluCst = 1.6765581f;

__global__ __launch_bounds__(256) void build_lut_kernel(
    const float* __restrict__ W1, const float* __restrict__ W2,
    float* __restrict__ table, unsigned* __restrict__ counter)
{
    if (blockIdx.x == 0 && threadIdx.x == 0) *counter = 0u;  // reset for this call

    // 32 lanes per LUT entry: lane k in [0,30) computes hidden unit k.
    int t = blockIdx.x * 256 + threadIdx.x;
    int entry = t >> 5;
    int k = t & 31;
    int kk = (k < 30) ? k : 29;              // clamp for safe loads; zeroed below

    float d  = (float)entry * (DMAXF / (float)TN);
    float t6 = 6.0f * d;                      // centers at t6 = 1..20, width 1 (step=1/6)
    const float w1scale = 1.0f / (1.12f * sqrtf(20.0f)); // emb/1.12 and W1/sqrt(20) folded

    float a = 0.0f;
    #pragma unroll
    for (int j = 0; j < 20; ++j) {
        float df = t6 - (float)(j + 1);
        float e  = __expf(-df * df);
        a = fmaf(e * w1scale, W1[j * 30 + kk], a);
    }
    float s = a / (1.0f + __expf(-a));        // silu

    float w2s = 0.0f;
    #pragma unroll
    for (int c = 0; c < 5; ++c) w2s += W2[kk * 5 + c];

    float contrib = (k < 30) ? s * w2s * (kSiluCst / sqrtf(30.0f)) : 0.0f;

    #pragma unroll
    for (int m = 16; m > 0; m >>= 1) contrib += __shfl_xor(contrib, m, 32);

    if (k == 0 && entry < TN) table[entry] = contrib;
}

__global__ __launch_bounds__(TPB) void edge_sum_kernel(
    const float* __restrict__ pos, const float* __restrict__ xr,
    const float* __restrict__ xl, const int* __restrict__ oi,
    const float* __restrict__ table, double* __restrict__ partials,
    unsigned* __restrict__ counter, float* __restrict__ out, int E)
{
    __shared__ float lut[TN];
    __shared__ double swv[TPB / 64];
    __shared__ double sm[TPB];
    __shared__ int slast;

    {   // stage 8KB LUT: 2 float4 per thread
        const float4* t4 = (const float4*)table;
        float4* l4 = (float4*)lut;
        l4[threadIdx.x]       = t4[threadIdx.x];
        l4[threadIdx.x + TPB] = t4[threadIdx.x + TPB];
    }
    __syncthreads();

    const float scale = (float)TN / DMAXF;
    const float umax  = (float)(TN - 1) - 1e-3f;

    int  gtid = blockIdx.x * TPB + threadIdx.x;
    long base = (long)gtid * EPT;
    double acc = 0.0;

    if (base + EPT <= (long)E) {
        float p[EPT * 3]; float xrv[EPT]; int oiv[EPT];
        const float4* p4 = (const float4*)(pos + base * 3);
        float4 t;
        t = p4[0]; p[0]  = t.x; p[1]  = t.y; p[2]  = t.z; p[3]  = t.w;
        t = p4[1]; p[4]  = t.x; p[5]  = t.y; p[6]  = t.z; p[7]  = t.w;
        t = p4[2]; p[8]  = t.x; p[9]  = t.y; p[10] = t.z; p[11] = t.w;
        t = p4[3]; p[12] = t.x; p[13] = t.y; p[14] = t.z; p[15] = t.w;
        t = p4[4]; p[16] = t.x; p[17] = t.y; p[18] = t.z; p[19] = t.w;
        t = p4[5]; p[20] = t.x; p[21] = t.y; p[22] = t.z; p[23] = t.w;
        const float4* x4 = (const float4*)(xr + base);
        t = x4[0]; xrv[0] = t.x; xrv[1] = t.y; xrv[2] = t.z; xrv[3] = t.w;
        t = x4[1]; xrv[4] = t.x; xrv[5] = t.y; xrv[6] = t.z; xrv[7] = t.w;
        const int4* o4 = (const int4*)(oi + base);
        int4 ti;
        ti = o4[0]; oiv[0] = ti.x; oiv[1] = ti.y; oiv[2] = ti.z; oiv[3] = ti.w;
        ti = o4[1]; oiv[4] = ti.x; oiv[5] = ti.y; oiv[6] = ti.z; oiv[7] = ti.w;

        float xlv[EPT];
        #pragma unroll
        for (int j = 0; j < EPT; ++j) xlv[j] = xl[oiv[j]];

        #pragma unroll
        for (int j = 0; j < EPT; ++j) {
            float x = p[3 * j], y = p[3 * j + 1], z = p[3 * j + 2];
            float d  = sqrtf(fmaf(x, x, fmaf(y, y, z * z)));
            float u  = fminf(d * scale, umax);
            int   i0 = (int)u;
            float fr = u - (float)i0;
            float f0 = lut[i0], f1 = lut[i0 + 1];
            float f  = fmaf(fr, f1 - f0, f0);
            acc += (double)(f * xrv[j] * xlv[j]);
        }
    } else if (base < (long)E) {
        for (long e = base; e < (long)E; ++e) {
            float x = pos[3 * e], y = pos[3 * e + 1], z = pos[3 * e + 2];
            float d  = sqrtf(fmaf(x, x, fmaf(y, y, z * z)));
            float u  = fminf(d * scale, umax);
            int   i0 = (int)u;
            float fr = u - (float)i0;
            float f  = fmaf(fr, lut[i0 + 1] - lut[i0], lut[i0]);
            acc += (double)(f * xr[e] * xl[oi[e]]);
        }
    }

    // deterministic block reduction
    #pragma unroll
    for (int off = 32; off > 0; off >>= 1) acc += __shfl_down(acc, off);
    int lane = threadIdx.x & 63, wv = threadIdx.x >> 6;
    if (lane == 0) swv[wv] = acc;
    __syncthreads();
    if (threadIdx.x == 0) {
        partials[blockIdx.x] = (swv[0] + swv[1]) + (swv[2] + swv[3]);
        __threadfence();
        unsigned prev = atomicAdd(counter, 1u);
        slast = (prev == (unsigned)(gridDim.x - 1)) ? 1 : 0;
    }
    __syncthreads();

    if (slast) {   // block-uniform: last block does the (deterministic) final sum
        __threadfence();
        double a = 0.0;
        for (int i = threadIdx.x; i < NBLK; i += TPB) a += partials[i];
        sm[threadIdx.x] = a;
        __syncthreads();
        #pragma unroll
        for (int s = 128; s > 0; s >>= 1) {
            if (threadIdx.x < (unsigned)s) sm[threadIdx.x] += sm[threadIdx.x + s];
            __syncthreads();
        }
        if (threadIdx.x == 0) out[0] = (float)sm[0];
    }
}

extern "C" void kernel_launch(void* const* d_in, const int* in_sizes, int n_in,
                              void* d_out, int out_size, void* d_ws, size_t ws_size,
                              hipStream_t stream) {
    const float* pos = (const float*)d_in[0];   // [E,3]
    const float* xr  = (const float*)d_in[1];   // [E,1]
    const float* xl  = (const float*)d_in[2];   // [N,1]
    const float* W1  = (const float*)d_in[3];   // [20,30]
    const float* W2  = (const float*)d_in[4];   // [30,5]
    const int*   oi  = (const int*)d_in[5];     // [E]
    float* out = (float*)d_out;

    int E = in_sizes[1];

    float*    table    = (float*)d_ws;
    double*   partials = (double*)((char*)d_ws + (size_t)TN * sizeof(float));
    unsigned* counter  = (unsigned*)((char*)d_ws + (size_t)TN * sizeof(float)
                                     + (size_t)NBLK * sizeof(double));

    hipLaunchKernelGGL(build_lut_kernel, dim3((TN * 32) / 256), dim3(256), 0, stream,
                       W1, W2, table, counter);
    hipLaunchKernelGGL(edge_sum_kernel, dim3(NBLK), dim3(TPB), 0, stream,
                       pos, xr, xl, oi, table, partials, counter, out, E);
}

// Round 3
// 28.784 us; speedup vs baseline: 1.9112x; 1.9112x over previous
//
#include <hip/hip_runtime.h>

// InvariantPolynomial: out = sum_e xl[oi[e]] * xr[e] * f(|pos_e|)
// f depends only on d=|pos| (sh[:, :1] == 1); tabulated in a 2048-entry LUT
// over [0,5] (f==0 in fp32 beyond d=5), linear interp (rel err ~1e-4 << 2e-2 tol).
//
// R3: no __threadfence / no fused last-block reduce (device-scope fence on
// gfx950 = per-block L2 writeback across non-coherent XCDs -> R2's 60us stall).
// Interleaved grid-stride scalar loads (wave-coalesced), 4096 blocks.
//
// ws layout: [0,8KB) float LUT; [8KB, 8KB+4096*8) double partials. Needs 40KB.

#define TN   2048
#define DMAXF 5.0f
#define NBLK 4096
#define TPB  256

// 1/sqrt(E[silu(z)^2]), z~N(0,1); matched reference exactly (absmax 0.0 R1/R2).
__device__ __constant__ float kSiluCst = 1.6765581f;

__global__ __launch_bounds__(256) void build_lut_kernel(
    const float* __restrict__ W1, const float* __restrict__ W2,
    float* __restrict__ table)
{
    // 32 lanes per LUT entry: lane k in [0,30) computes hidden unit k.
    int t = blockIdx.x * 256 + threadIdx.x;
    int entry = t >> 5;
    int k = t & 31;
    int kk = (k < 30) ? k : 29;              // clamp for safe loads; zeroed below

    float d  = (float)entry * (DMAXF / (float)TN);
    float t6 = 6.0f * d;                      // centers at t6 = 1..20, width 1 (step=1/6)
    const float w1scale = 1.0f / (1.12f * sqrtf(20.0f)); // emb/1.12, W1/sqrt(20) folded

    float a = 0.0f;
    #pragma unroll
    for (int j = 0; j < 20; ++j) {
        float df = t6 - (float)(j + 1);
        float e  = __expf(-df * df);
        a = fmaf(e * w1scale, W1[j * 30 + kk], a);
    }
    float s = a / (1.0f + __expf(-a));        // silu

    float w2s = 0.0f;
    #pragma unroll
    for (int c = 0; c < 5; ++c) w2s += W2[kk * 5 + c];

    float contrib = (k < 30) ? s * w2s * (kSiluCst / sqrtf(30.0f)) : 0.0f;

    #pragma unroll
    for (int m = 16; m > 0; m >>= 1) contrib += __shfl_xor(contrib, m, 32);

    if (k == 0 && entry < TN) table[entry] = contrib;
}

__global__ __launch_bounds__(TPB) void edge_sum_kernel(
    const float* __restrict__ pos, const float* __restrict__ xr,
    const float* __restrict__ xl, const int* __restrict__ oi,
    const float* __restrict__ table, double* __restrict__ partials, int E)
{
    __shared__ float lut[TN];
    __shared__ double swv[TPB / 64];

    {   // stage 8KB LUT: 2 float4 per thread
        const float4* t4 = (const float4*)table;
        float4* l4 = (float4*)lut;
        l4[threadIdx.x]       = t4[threadIdx.x];
        l4[threadIdx.x + TPB] = t4[threadIdx.x + TPB];
    }
    __syncthreads();

    const float scale = (float)TN / DMAXF;
    const float umax  = (float)(TN - 1) - 1e-3f;

    double acc = 0.0;
    int stride = gridDim.x * TPB;
    for (int e = blockIdx.x * TPB + threadIdx.x; e < E; e += stride) {
        // interleaved: lane-consecutive e -> coalesced scalar streams
        float x = pos[3 * e + 0];
        float y = pos[3 * e + 1];
        float z = pos[3 * e + 2];
        float d  = sqrtf(fmaf(x, x, fmaf(y, y, z * z)));
        float u  = fminf(d * scale, umax);     // clamp: f ~ 0 out there
        int   i0 = (int)u;
        float fr = u - (float)i0;
        float f0 = lut[i0];
        float f1 = lut[i0 + 1];
        float f  = fmaf(fr, f1 - f0, f0);
        acc += (double)(f * xr[e] * xl[oi[e]]);
    }

    // deterministic block reduction (wave shfl + LDS across 4 waves)
    #pragma unroll
    for (int off = 32; off > 0; off >>= 1) acc += __shfl_down(acc, off);
    int lane = threadIdx.x & 63, wv = threadIdx.x >> 6;
    if (lane == 0) swv[wv] = acc;
    __syncthreads();
    if (threadIdx.x == 0)
        partials[blockIdx.x] = (swv[0] + swv[1]) + (swv[2] + swv[3]);
}

__global__ __launch_bounds__(256) void final_reduce_kernel(
    const double* __restrict__ partials, int n, float* __restrict__ out)
{
    __shared__ double sm[256];
    double a = 0.0;
    for (int i = threadIdx.x; i < n; i += 256) a += partials[i];
    sm[threadIdx.x] = a;
    __syncthreads();
    #pragma unroll
    for (int s = 128; s > 0; s >>= 1) {
        if (threadIdx.x < (unsigned)s) sm[threadIdx.x] += sm[threadIdx.x + s];
        __syncthreads();
    }
    if (threadIdx.x == 0) out[0] = (float)sm[0];
}

extern "C" void kernel_launch(void* const* d_in, const int* in_sizes, int n_in,
                              void* d_out, int out_size, void* d_ws, size_t ws_size,
                              hipStream_t stream) {
    const float* pos = (const float*)d_in[0];   // [E,3]
    const float* xr  = (const float*)d_in[1];   // [E,1]
    const float* xl  = (const float*)d_in[2];   // [N,1]
    const float* W1  = (const float*)d_in[3];   // [20,30]
    const float* W2  = (const float*)d_in[4];   // [30,5]
    const int*   oi  = (const int*)d_in[5];     // [E]
    float* out = (float*)d_out;

    int E = in_sizes[1];

    float*  table    = (float*)d_ws;
    double* partials = (double*)((char*)d_ws + (size_t)TN * sizeof(float));

    hipLaunchKernelGGL(build_lut_kernel, dim3((TN * 32) / 256), dim3(256), 0, stream,
                       W1, W2, table);
    hipLaunchKernelGGL(edge_sum_kernel, dim3(NBLK), dim3(TPB), 0, stream,
                       pos, xr, xl, oi, table, partials, E);
    hipLaunchKernelGGL(final_reduce_kernel, dim3(1), dim3(256), 0, stream,
                       partials, NBLK, out);
}